// Round 1
// baseline (2671.227 us; speedup 1.0000x reference)
//
#include <hip/hip_runtime.h>
#include <hip/hip_bf16.h>
#include <math.h>

// ---------- types ----------
typedef __attribute__((ext_vector_type(8))) short short8;   // 8 x bf16 (4 VGPRs)
typedef __attribute__((ext_vector_type(4))) float f32x4;    // MFMA accumulator

// B=16, H=W=64 -> N=4096 tokens/batch, C=256, M = B*N = 65536
#define NTOK 4096
#define CDIM 256
#define MROWS 65536

static __device__ __forceinline__ unsigned short f2bf(float f) {
    union { float f; unsigned int u; } v; v.f = f;
    unsigned int u = v.u;
    return (unsigned short)((u + 0x7fffu + ((u >> 16) & 1u)) >> 16);  // RNE
}

// ---------- kernel 1: transpose + convert weights to bf16 ----------
// wt_all[z][c_out][c_in] = w_z[c_in][c_out], z in {q,k,v,p}
__global__ __launch_bounds__(256) void prep_w_kernel(
    const float* __restrict__ wq, const float* __restrict__ wk,
    const float* __restrict__ wv, const float* __restrict__ wp,
    unsigned short* __restrict__ wt_all)
{
    const int o = blockIdx.x;      // c_out
    const int t = threadIdx.x;     // c_in
    const int z = blockIdx.y;
    const float* w = (z == 0) ? wq : (z == 1) ? wk : (z == 2) ? wv : wp;
    wt_all[z * 65536 + o * 256 + t] = f2bf(w[t * 256 + o]);
}

// ---------- kernel 2: QKV projections ----------
// grid (M/64, 3). z=0 -> Q (row-major bf16), z=1 -> K (row-major bf16),
// z=2 -> V transposed [B][C][N] bf16.
__global__ __launch_bounds__(256) void qkv_kernel(
    const float* __restrict__ x,
    const unsigned short* __restrict__ wt_all,
    const float* __restrict__ bq, const float* __restrict__ bk,
    const float* __restrict__ bvp,
    unsigned short* __restrict__ q_ws, unsigned short* __restrict__ k_ws,
    unsigned short* __restrict__ vt_ws)
{
    __shared__ unsigned short xs[64 * 256];   // 32 KiB
    const int t = threadIdx.x;
    const int z = blockIdx.y;
    const long m0 = (long)blockIdx.x * 64;

    // stage X tile (fp32 -> bf16) into LDS, coalesced float4 loads
    #pragma unroll
    for (int i = 0; i < 16; ++i) {
        int idx = i * 256 + t;
        int row = idx >> 6;
        int c4 = (idx & 63) << 2;
        float4 v = *reinterpret_cast<const float4*>(x + (m0 + row) * CDIM + c4);
        ushort4 pk;
        pk.x = f2bf(v.x); pk.y = f2bf(v.y); pk.z = f2bf(v.z); pk.w = f2bf(v.w);
        *reinterpret_cast<ushort4*>(&xs[row * 256 + c4]) = pk;
    }
    __syncthreads();

    const int wave = t >> 6, lane = t & 63;
    const int lr = lane & 15, lh = lane >> 4;

    // A fragments: 16 rows x 256 K, 8 chunks of K=32
    short8 a_frag[8];
    #pragma unroll
    for (int kk = 0; kk < 8; ++kk)
        a_frag[kk] = *reinterpret_cast<const short8*>(
            &xs[(wave * 16 + lr) * 256 + kk * 32 + lh * 8]);

    const unsigned short* wt = wt_all + z * 65536;
    f32x4 acc[16];
    #pragma unroll
    for (int cb = 0; cb < 16; ++cb) acc[cb] = (f32x4)(0.0f);

    for (int kk = 0; kk < 8; ++kk) {
        #pragma unroll
        for (int cb = 0; cb < 16; ++cb) {
            short8 b_frag = *reinterpret_cast<const short8*>(
                &wt[(cb * 16 + lr) * 256 + kk * 32 + lh * 8]);
            acc[cb] = __builtin_amdgcn_mfma_f32_16x16x32_bf16(a_frag[kk], b_frag, acc[cb], 0, 0, 0);
        }
    }

    if (z == 0 || z == 1) {
        const float* bias = (z == 0) ? bq : bk;
        unsigned short* out = (z == 0) ? q_ws : k_ws;
        #pragma unroll
        for (int cb = 0; cb < 16; ++cb) {
            int c = cb * 16 + lr;
            float bb = bias[c];
            #pragma unroll
            for (int r = 0; r < 4; ++r) {
                long row = m0 + wave * 16 + lh * 4 + r;
                out[row * 256 + c] = f2bf(acc[cb][r] + bb);
            }
        }
    } else {
        // V: bias add, then transpose through LDS -> vt_ws[B][C][N]
        __syncthreads();  // everyone done reading xs (a_frags are in regs)
        #pragma unroll
        for (int cb = 0; cb < 16; ++cb) {
            int c = cb * 16 + lr;
            float bb = bvp[c];
            #pragma unroll
            for (int r = 0; r < 4; ++r)
                xs[(wave * 16 + lh * 4 + r) * 256 + c] = f2bf(acc[cb][r] + bb);
        }
        __syncthreads();
        // thread t owns column c=t; write 64 consecutive n values
        const int bb_ = (int)(m0 >> 12);
        const int n0 = (int)(m0 & 4095);
        unsigned short* dst = vt_ws + ((long)bb_ * 256 + t) * NTOK + n0;
        #pragma unroll
        for (int rc = 0; rc < 8; ++rc) {
            short8 pk;
            #pragma unroll
            for (int j = 0; j < 8; ++j)
                pk[j] = (short)xs[(rc * 8 + j) * 256 + t];
            *reinterpret_cast<short8*>(dst + rc * 8) = pk;
        }
    }
}

// ---------- kernel 3: flash attention ----------
// grid (N/64, B), 4 waves/block, wave owns 16 Q rows, KV tile = 32.
__global__ __launch_bounds__(256) void attn_kernel(
    const unsigned short* __restrict__ q_ws,
    const unsigned short* __restrict__ k_ws,
    const unsigned short* __restrict__ vt_ws,
    unsigned short* __restrict__ o_ws)
{
    __shared__ unsigned short p_lds[4 * 16 * 32];
    const int t = threadIdx.x;
    const int wave = t >> 6, lane = t & 63;
    const int lr = lane & 15, lh = lane >> 4;
    const int b = blockIdx.y;
    const int q0 = blockIdx.x * 64 + wave * 16;
    const long qbase = (long)b * NTOK + q0;

    short8 q_frag[8];
    #pragma unroll
    for (int kk = 0; kk < 8; ++kk)
        q_frag[kk] = *reinterpret_cast<const short8*>(
            &q_ws[(qbase + lr) * CDIM + kk * 32 + lh * 8]);

    f32x4 acc[16];
    #pragma unroll
    for (int cb = 0; cb < 16; ++cb) acc[cb] = (f32x4)(0.0f);
    float m_run[4] = {-INFINITY, -INFINITY, -INFINITY, -INFINITY};
    float l_run[4] = {0.f, 0.f, 0.f, 0.f};

    const unsigned short* kbase = k_ws + (long)b * NTOK * CDIM;
    const unsigned short* vbase = vt_ws + (long)b * CDIM * NTOK;
    unsigned short* my_p = p_lds + wave * 512;

    for (int kv0 = 0; kv0 < NTOK; kv0 += 32) {
        f32x4 s0 = (f32x4)(0.0f), s1 = (f32x4)(0.0f);
        #pragma unroll
        for (int kk = 0; kk < 8; ++kk) {
            short8 kf0 = *reinterpret_cast<const short8*>(
                &kbase[(long)(kv0 + lr) * CDIM + kk * 32 + lh * 8]);
            short8 kf1 = *reinterpret_cast<const short8*>(
                &kbase[(long)(kv0 + 16 + lr) * CDIM + kk * 32 + lh * 8]);
            s0 = __builtin_amdgcn_mfma_f32_16x16x32_bf16(q_frag[kk], kf0, s0, 0, 0, 0);
            s1 = __builtin_amdgcn_mfma_f32_16x16x32_bf16(q_frag[kk], kf1, s1, 0, 0, 0);
        }

        // online softmax update (rows live in 16-lane groups; D-layout row=(lh*4+r))
        float alpha[4], p0[4], p1[4];
        #pragma unroll
        for (int r = 0; r < 4; ++r) {
            float s0r = s0[r] * 0.0625f;  // scale = C^-0.5 = 1/16
            float s1r = s1[r] * 0.0625f;
            float mt = fmaxf(s0r, s1r);
            mt = fmaxf(mt, __shfl_xor(mt, 1));
            mt = fmaxf(mt, __shfl_xor(mt, 2));
            mt = fmaxf(mt, __shfl_xor(mt, 4));
            mt = fmaxf(mt, __shfl_xor(mt, 8));
            float m_new = fmaxf(m_run[r], mt);
            float a = __expf(m_run[r] - m_new);   // exp(-inf)=0 on first tile
            float e0 = __expf(s0r - m_new);
            float e1 = __expf(s1r - m_new);
            float rs = e0 + e1;
            rs += __shfl_xor(rs, 1);
            rs += __shfl_xor(rs, 2);
            rs += __shfl_xor(rs, 4);
            rs += __shfl_xor(rs, 8);
            l_run[r] = l_run[r] * a + rs;
            m_run[r] = m_new;
            alpha[r] = a;
            p0[r] = e0; p1[r] = e1;
        }
        #pragma unroll
        for (int cb = 0; cb < 16; ++cb) {
            acc[cb][0] *= alpha[0];
            acc[cb][1] *= alpha[1];
            acc[cb][2] *= alpha[2];
            acc[cb][3] *= alpha[3];
        }

        // P (D-layout) -> LDS -> A-layout fragment
        #pragma unroll
        for (int r = 0; r < 4; ++r) {
            my_p[(lh * 4 + r) * 32 + lr]      = f2bf(p0[r]);
            my_p[(lh * 4 + r) * 32 + 16 + lr] = f2bf(p1[r]);
        }
        asm volatile("s_waitcnt lgkmcnt(0)" ::: "memory");
        short8 pa = *reinterpret_cast<const short8*>(&my_p[lr * 32 + lh * 8]);

        // PV: out[16 x 256] += P[16 x 32] @ V[32 x 256]
        #pragma unroll
        for (int cb = 0; cb < 16; ++cb) {
            short8 vf = *reinterpret_cast<const short8*>(
                &vbase[(long)(cb * 16 + lr) * NTOK + kv0 + lh * 8]);
            acc[cb] = __builtin_amdgcn_mfma_f32_16x16x32_bf16(pa, vf, acc[cb], 0, 0, 0);
        }
    }

    #pragma unroll
    for (int cb = 0; cb < 16; ++cb) {
        int c = cb * 16 + lr;
        #pragma unroll
        for (int r = 0; r < 4; ++r) {
            float o = acc[cb][r] / l_run[r];
            o_ws[(qbase + lh * 4 + r) * CDIM + c] = f2bf(o);
        }
    }
}

// ---------- kernel 4: output projection + residual ----------
__global__ __launch_bounds__(256) void proj_kernel(
    const unsigned short* __restrict__ o_ws,
    const unsigned short* __restrict__ wpt,
    const float* __restrict__ bp,
    const float* __restrict__ x,
    float* __restrict__ out)
{
    const int t = threadIdx.x;
    const int wave = t >> 6, lane = t & 63;
    const int lr = lane & 15, lh = lane >> 4;
    const long m0 = (long)blockIdx.x * 64 + wave * 16;

    short8 a_frag[8];
    #pragma unroll
    for (int kk = 0; kk < 8; ++kk)
        a_frag[kk] = *reinterpret_cast<const short8*>(
            &o_ws[(m0 + lr) * CDIM + kk * 32 + lh * 8]);

    f32x4 acc[16];
    #pragma unroll
    for (int cb = 0; cb < 16; ++cb) acc[cb] = (f32x4)(0.0f);

    for (int kk = 0; kk < 8; ++kk) {
        #pragma unroll
        for (int cb = 0; cb < 16; ++cb) {
            short8 b_frag = *reinterpret_cast<const short8*>(
                &wpt[(cb * 16 + lr) * 256 + kk * 32 + lh * 8]);
            acc[cb] = __builtin_amdgcn_mfma_f32_16x16x32_bf16(a_frag[kk], b_frag, acc[cb], 0, 0, 0);
        }
    }

    #pragma unroll
    for (int cb = 0; cb < 16; ++cb) {
        int c = cb * 16 + lr;
        float bias = bp[c];
        #pragma unroll
        for (int r = 0; r < 4; ++r) {
            long row = m0 + lh * 4 + r;
            out[row * CDIM + c] = acc[cb][r] + bias + x[row * CDIM + c];
        }
    }
}

extern "C" void kernel_launch(void* const* d_in, const int* in_sizes, int n_in,
                              void* d_out, int out_size, void* d_ws, size_t ws_size,
                              hipStream_t stream) {
    const float* x  = (const float*)d_in[0];
    const float* wq = (const float*)d_in[1];
    const float* bq = (const float*)d_in[2];
    const float* wk = (const float*)d_in[3];
    const float* bk = (const float*)d_in[4];
    const float* wv = (const float*)d_in[5];
    const float* bv = (const float*)d_in[6];
    const float* wp = (const float*)d_in[7];
    const float* bp = (const float*)d_in[8];
    float* out = (float*)d_out;

    char* ws = (char*)d_ws;
    unsigned short* wt_all = (unsigned short*)ws;              // 4*65536*2B = 512 KiB
    unsigned short* q_ws   = (unsigned short*)(ws + 524288);   // 32 MiB each below
    unsigned short* k_ws   = q_ws + (size_t)MROWS * CDIM;
    unsigned short* vt_ws  = k_ws + (size_t)MROWS * CDIM;
    unsigned short* o_ws   = vt_ws + (size_t)MROWS * CDIM;

    prep_w_kernel<<<dim3(256, 4), 256, 0, stream>>>(wq, wk, wv, wp, wt_all);
    qkv_kernel<<<dim3(MROWS / 64, 3), 256, 0, stream>>>(x, wt_all, bq, bk, bv,
                                                        q_ws, k_ws, vt_ws);
    attn_kernel<<<dim3(NTOK / 64, 16), 256, 0, stream>>>(q_ws, k_ws, vt_ws, o_ws);
    proj_kernel<<<dim3(MROWS / 64), 256, 0, stream>>>(o_ws, wt_all + 3 * 65536, bp, x, out);
}

// Round 2
// 1019.020 us; speedup vs baseline: 2.6214x; 2.6214x over previous
//
#include <hip/hip_runtime.h>
#include <hip/hip_bf16.h>
#include <math.h>

// ---------- types ----------
typedef __attribute__((ext_vector_type(8))) short short8;   // 8 x bf16 (4 VGPRs)
typedef __attribute__((ext_vector_type(4))) float f32x4;    // MFMA accumulator

// B=16, H=W=64 -> N=4096 tokens/batch, C=256, M = B*N = 65536
#define NTOK 4096
#define CDIM 256
#define MROWS 65536
#define KVBLK 64
#define NT (NTOK / KVBLK)

static __device__ __forceinline__ unsigned short f2bf(float f) {
    union { float f; unsigned int u; } v; v.f = f;
    unsigned int u = v.u;
    return (unsigned short)((u + 0x7fffu + ((u >> 16) & 1u)) >> 16);  // RNE
}

// ---------- kernel 1: transpose + convert weights to bf16 ----------
// wt_all[z][c_out][c_in] = w_z[c_in][c_out]; z=0 (Wq) folds in the 1/16 scale.
__global__ __launch_bounds__(256) void prep_w_kernel(
    const float* __restrict__ wq, const float* __restrict__ wk,
    const float* __restrict__ wv, const float* __restrict__ wp,
    unsigned short* __restrict__ wt_all)
{
    const int o = blockIdx.x;      // c_out
    const int t = threadIdx.x;     // c_in
    const int z = blockIdx.y;
    const float* w = (z == 0) ? wq : (z == 1) ? wk : (z == 2) ? wv : wp;
    const float s = (z == 0) ? 0.0625f : 1.0f;   // fold softmax scale into Q
    wt_all[z * 65536 + o * 256 + t] = f2bf(w[t * 256 + o] * s);
}

// ---------- kernel 2: merged QKV projections (X staged once) ----------
__global__ __launch_bounds__(256) void qkv_kernel(
    const float* __restrict__ x,
    const unsigned short* __restrict__ wt_all,
    const float* __restrict__ bq, const float* __restrict__ bk,
    const float* __restrict__ bv,
    unsigned short* __restrict__ q_ws, unsigned short* __restrict__ k_ws,
    unsigned short* __restrict__ vt_ws)
{
    __shared__ unsigned short xs[64 * 256];   // 32 KiB
    const int t = threadIdx.x;
    const long m0 = (long)blockIdx.x * 64;

    // stage X tile (fp32 -> bf16) into LDS, coalesced float4 loads
    #pragma unroll
    for (int i = 0; i < 16; ++i) {
        int idx = i * 256 + t;
        int row = idx >> 6;
        int c4 = (idx & 63) << 2;
        float4 v = *reinterpret_cast<const float4*>(x + (m0 + row) * CDIM + c4);
        ushort4 pk;
        pk.x = f2bf(v.x); pk.y = f2bf(v.y); pk.z = f2bf(v.z); pk.w = f2bf(v.w);
        *reinterpret_cast<ushort4*>(&xs[row * 256 + c4]) = pk;
    }
    __syncthreads();

    const int wave = t >> 6, lane = t & 63;
    const int lr = lane & 15, lh = lane >> 4;

    // A fragments: 16 rows x 256 K (held across all three projections)
    short8 a_frag[8];
    #pragma unroll
    for (int kk = 0; kk < 8; ++kk)
        a_frag[kk] = *reinterpret_cast<const short8*>(
            &xs[(wave * 16 + lr) * 256 + kk * 32 + lh * 8]);

    for (int z = 0; z < 3; ++z) {
        const unsigned short* wt = wt_all + z * 65536;
        f32x4 acc[16];
        #pragma unroll
        for (int cb = 0; cb < 16; ++cb) acc[cb] = (f32x4)(0.0f);

        for (int kk = 0; kk < 8; ++kk) {
            #pragma unroll
            for (int cb = 0; cb < 16; ++cb) {
                short8 b_frag = *reinterpret_cast<const short8*>(
                    &wt[(cb * 16 + lr) * 256 + kk * 32 + lh * 8]);
                acc[cb] = __builtin_amdgcn_mfma_f32_16x16x32_bf16(a_frag[kk], b_frag, acc[cb], 0, 0, 0);
            }
        }

        if (z == 0 || z == 1) {
            const float* bias = (z == 0) ? bq : bk;
            const float bs = (z == 0) ? 0.0625f : 1.0f;
            unsigned short* out = (z == 0) ? q_ws : k_ws;
            #pragma unroll
            for (int cb = 0; cb < 16; ++cb) {
                int c = cb * 16 + lr;
                float bb = bias[c] * bs;
                #pragma unroll
                for (int r = 0; r < 4; ++r) {
                    long row = m0 + wave * 16 + lh * 4 + r;
                    out[row * 256 + c] = f2bf(acc[cb][r] + bb);
                }
            }
        } else {
            // V: bias add, then transpose through LDS -> vt_ws[B][C][N]
            __syncthreads();
            #pragma unroll
            for (int cb = 0; cb < 16; ++cb) {
                int c = cb * 16 + lr;
                float bb = bv[c];
                #pragma unroll
                for (int r = 0; r < 4; ++r)
                    xs[(wave * 16 + lh * 4 + r) * 256 + c] = f2bf(acc[cb][r] + bb);
            }
            __syncthreads();
            const int bb_ = (int)(m0 >> 12);
            const int n0 = (int)(m0 & 4095);
            unsigned short* dst = vt_ws + ((long)bb_ * 256 + t) * NTOK + n0;
            #pragma unroll
            for (int rc = 0; rc < 8; ++rc) {
                short8 pk;
                #pragma unroll
                for (int j = 0; j < 8; ++j)
                    pk[j] = (short)xs[(rc * 8 + j) * 256 + t];
                *reinterpret_cast<short8*>(dst + rc * 8) = pk;
            }
        }
    }
}

// ---------- kernel 3: flash attention ----------
// 512 threads = 8 waves x 16 Q rows (QBLK=128), KVBLK=64.
// K/V staged in LDS (XOR-swizzled), reg-staged + double-buffered.
// Dynamic LDS: ks 2x32KB | vs 2x32KB | ps 8x2KB = 144KB.
__global__ __launch_bounds__(512, 2) void attn_kernel(
    const unsigned short* __restrict__ q_all,
    const unsigned short* __restrict__ k_all,
    const unsigned short* __restrict__ vt_all,
    unsigned short* __restrict__ o_ws)
{
    extern __shared__ char smem[];
    char* ksb = smem;                 // [2][64 rows][512B], swz: chunk ^= row&7
    char* vsb = smem + 65536;         // [2][256 rows][128B], swz: chunk ^= c&7
    const int t = threadIdx.x;
    const int wave = t >> 6, lane = t & 63;
    const int lr = lane & 15, lh = lane >> 4;
    char* psb = smem + 131072 + wave * 2048;  // per-wave P [16 q][128B]

    // XCD-aware swizzle: keep a batch's 32 blocks on one XCD for K/V L2 hits
    const int bid = blockIdx.x;
    const int xcd = bid & 7, slot = bid >> 3;
    const int b = xcd + 8 * (slot >> 5);
    const int xblk = slot & 31;
    const int q0 = xblk * 128 + wave * 16;
    const long qbase = (long)b * NTOK + q0;

    const unsigned short* kg = k_all + (long)b * NTOK * CDIM;
    const unsigned short* vg = vt_all + (long)b * CDIM * NTOK;

    // Q fragments (held in regs for the whole kernel); 1/16 scale pre-folded
    short8 q_frag[8];
    #pragma unroll
    for (int kk = 0; kk < 8; ++kk)
        q_frag[kk] = *reinterpret_cast<const short8*>(
            &q_all[(qbase + lr) * CDIM + kk * 32 + lh * 8]);

    // staging registers (tile t+1 in flight while computing tile t)
    short8 kreg[4], vreg[4];
    auto gload = [&](int kv0) {
        #pragma unroll
        for (int i = 0; i < 4; ++i) {
            int row = wave * 8 + i * 2 + (lane >> 5);
            kreg[i] = *reinterpret_cast<const short8*>(
                &kg[(long)(kv0 + row) * CDIM + (lane & 31) * 8]);
        }
        #pragma unroll
        for (int i = 0; i < 4; ++i) {
            int c = wave * 32 + i * 8 + (lane >> 3);
            vreg[i] = *reinterpret_cast<const short8*>(
                &vg[(long)c * NTOK + kv0 + (lane & 7) * 8]);
        }
    };
    auto dswrite = [&](int buf) {
        char* kb = ksb + buf * 32768;
        char* vb = vsb + buf * 32768;
        #pragma unroll
        for (int i = 0; i < 4; ++i) {
            int row = wave * 8 + i * 2 + (lane >> 5);
            *reinterpret_cast<short8*>(
                kb + row * 512 + (((lane & 31) ^ (row & 7)) * 16)) = kreg[i];
        }
        #pragma unroll
        for (int i = 0; i < 4; ++i) {
            int c = wave * 32 + i * 8 + (lane >> 3);
            *reinterpret_cast<short8*>(
                vb + c * 128 + (((lane & 7) ^ (c & 7)) * 16)) = vreg[i];
        }
    };

    f32x4 acc[16];
    #pragma unroll
    for (int cb = 0; cb < 16; ++cb) acc[cb] = (f32x4)(0.0f);
    float m_run[4] = {-INFINITY, -INFINITY, -INFINITY, -INFINITY};
    float l_run[4] = {0.f, 0.f, 0.f, 0.f};

    // prologue: tile 0 -> buf0; issue tile 1 loads
    gload(0);
    dswrite(0);
    gload(KVBLK);
    __syncthreads();

    for (int tI = 0; tI < NT; ++tI) {
        char* kb = ksb + (tI & 1) * 32768;
        char* vb = vsb + (tI & 1) * 32768;

        // ---- QK^T: S[16 q][64 k] ----
        f32x4 s[4];
        #pragma unroll
        for (int n16 = 0; n16 < 4; ++n16) s[n16] = (f32x4)(0.0f);
        __builtin_amdgcn_s_setprio(1);
        #pragma unroll
        for (int kk = 0; kk < 8; ++kk) {
            #pragma unroll
            for (int n16 = 0; n16 < 4; ++n16) {
                int row = n16 * 16 + lr;
                short8 kf = *reinterpret_cast<const short8*>(
                    kb + row * 512 + (((kk * 4 + lh) ^ (row & 7)) * 16));
                s[n16] = __builtin_amdgcn_mfma_f32_16x16x32_bf16(q_frag[kk], kf, s[n16], 0, 0, 0);
            }
        }
        __builtin_amdgcn_s_setprio(0);

        // ---- online softmax (row q = lh*4+r lives in 16-lane group) ----
        float alpha[4], p[4][4];
        #pragma unroll
        for (int r = 0; r < 4; ++r) {
            float v0 = s[0][r], v1 = s[1][r], v2 = s[2][r], v3 = s[3][r];
            float mt = fmaxf(fmaxf(v0, v1), fmaxf(v2, v3));
            mt = fmaxf(mt, __shfl_xor(mt, 1));
            mt = fmaxf(mt, __shfl_xor(mt, 2));
            mt = fmaxf(mt, __shfl_xor(mt, 4));
            mt = fmaxf(mt, __shfl_xor(mt, 8));
            float m_new = fmaxf(m_run[r], mt);
            float a = __expf(m_run[r] - m_new);   // exp(-inf)=0 on first tile
            float e0 = __expf(v0 - m_new);
            float e1 = __expf(v1 - m_new);
            float e2 = __expf(v2 - m_new);
            float e3 = __expf(v3 - m_new);
            float rs = (e0 + e1) + (e2 + e3);
            rs += __shfl_xor(rs, 1);
            rs += __shfl_xor(rs, 2);
            rs += __shfl_xor(rs, 4);
            rs += __shfl_xor(rs, 8);
            l_run[r] = l_run[r] * a + rs;
            m_run[r] = m_new;
            alpha[r] = a;
            p[0][r] = e0; p[1][r] = e1; p[2][r] = e2; p[3][r] = e3;
        }
        #pragma unroll
        for (int cb = 0; cb < 16; ++cb) {
            acc[cb][0] *= alpha[0];
            acc[cb][1] *= alpha[1];
            acc[cb][2] *= alpha[2];
            acc[cb][3] *= alpha[3];
        }

        // ---- P (D-layout) -> swizzled LDS ----
        #pragma unroll
        for (int r = 0; r < 4; ++r) {
            int q = lh * 4 + r;
            #pragma unroll
            for (int n16 = 0; n16 < 4; ++n16) {
                int col = n16 * 16 + lr;
                *reinterpret_cast<unsigned short*>(
                    psb + q * 128 + (((col >> 3) ^ (q & 7)) * 16) + (col & 7) * 2)
                    = f2bf(p[n16][r]);
            }
        }

        // ---- stage next tile while P writes land ----
        if (tI + 1 < NT) dswrite((tI + 1) & 1);
        if (tI + 2 < NT) gload((tI + 2) * KVBLK);

        asm volatile("s_waitcnt lgkmcnt(0)" ::: "memory");
        short8 pa0 = *reinterpret_cast<const short8*>(
            psb + lr * 128 + (((0 + lh) ^ (lr & 7)) * 16));
        short8 pa1 = *reinterpret_cast<const short8*>(
            psb + lr * 128 + (((4 + lh) ^ (lr & 7)) * 16));

        // ---- PV: out[16 q][256 c] += P[16x64] @ V[64x256] ----
        __builtin_amdgcn_s_setprio(1);
        #pragma unroll
        for (int cb = 0; cb < 16; ++cb) {
            int c = cb * 16 + lr;
            short8 vf0 = *reinterpret_cast<const short8*>(
                vb + c * 128 + (((0 + lh) ^ (c & 7)) * 16));
            short8 vf1 = *reinterpret_cast<const short8*>(
                vb + c * 128 + (((4 + lh) ^ (c & 7)) * 16));
            acc[cb] = __builtin_amdgcn_mfma_f32_16x16x32_bf16(pa0, vf0, acc[cb], 0, 0, 0);
            acc[cb] = __builtin_amdgcn_mfma_f32_16x16x32_bf16(pa1, vf1, acc[cb], 0, 0, 0);
        }
        __builtin_amdgcn_s_setprio(0);
        __syncthreads();
    }

    // ---- epilogue ----
    float inv[4];
    #pragma unroll
    for (int r = 0; r < 4; ++r) inv[r] = 1.0f / l_run[r];
    #pragma unroll
    for (int cb = 0; cb < 16; ++cb) {
        int c = cb * 16 + lr;
        #pragma unroll
        for (int r = 0; r < 4; ++r)
            o_ws[(qbase + lh * 4 + r) * CDIM + c] = f2bf(acc[cb][r] * inv[r]);
    }
}

// ---------- kernel 4: output projection + residual ----------
__global__ __launch_bounds__(256) void proj_kernel(
    const unsigned short* __restrict__ o_ws,
    const unsigned short* __restrict__ wpt,
    const float* __restrict__ bp,
    const float* __restrict__ x,
    float* __restrict__ out)
{
    const int t = threadIdx.x;
    const int wave = t >> 6, lane = t & 63;
    const int lr = lane & 15, lh = lane >> 4;
    const long m0 = (long)blockIdx.x * 64 + wave * 16;

    short8 a_frag[8];
    #pragma unroll
    for (int kk = 0; kk < 8; ++kk)
        a_frag[kk] = *reinterpret_cast<const short8*>(
            &o_ws[(m0 + lr) * CDIM + kk * 32 + lh * 8]);

    f32x4 acc[16];
    #pragma unroll
    for (int cb = 0; cb < 16; ++cb) acc[cb] = (f32x4)(0.0f);

    for (int kk = 0; kk < 8; ++kk) {
        #pragma unroll
        for (int cb = 0; cb < 16; ++cb) {
            short8 b_frag = *reinterpret_cast<const short8*>(
                &wpt[(cb * 16 + lr) * 256 + kk * 32 + lh * 8]);
            acc[cb] = __builtin_amdgcn_mfma_f32_16x16x32_bf16(a_frag[kk], b_frag, acc[cb], 0, 0, 0);
        }
    }

    #pragma unroll
    for (int cb = 0; cb < 16; ++cb) {
        int c = cb * 16 + lr;
        float bias = bp[c];
        #pragma unroll
        for (int r = 0; r < 4; ++r) {
            long row = m0 + lh * 4 + r;
            out[row * CDIM + c] = acc[cb][r] + bias + x[row * CDIM + c];
        }
    }
}

extern "C" void kernel_launch(void* const* d_in, const int* in_sizes, int n_in,
                              void* d_out, int out_size, void* d_ws, size_t ws_size,
                              hipStream_t stream) {
    const float* x  = (const float*)d_in[0];
    const float* wq = (const float*)d_in[1];
    const float* bq = (const float*)d_in[2];
    const float* wk = (const float*)d_in[3];
    const float* bk = (const float*)d_in[4];
    const float* wv = (const float*)d_in[5];
    const float* bv = (const float*)d_in[6];
    const float* wp = (const float*)d_in[7];
    const float* bp = (const float*)d_in[8];
    float* out = (float*)d_out;

    char* ws = (char*)d_ws;
    unsigned short* wt_all = (unsigned short*)ws;              // 512 KiB
    unsigned short* q_ws   = (unsigned short*)(ws + 524288);   // 32 MiB each below
    unsigned short* k_ws   = q_ws + (size_t)MROWS * CDIM;
    unsigned short* vt_ws  = k_ws + (size_t)MROWS * CDIM;
    unsigned short* o_ws   = vt_ws + (size_t)MROWS * CDIM;

    prep_w_kernel<<<dim3(256, 4), 256, 0, stream>>>(wq, wk, wv, wp, wt_all);
    qkv_kernel<<<dim3(MROWS / 64), 256, 0, stream>>>(x, wt_all, bq, bk, bv,
                                                     q_ws, k_ws, vt_ws);
    hipFuncSetAttribute((const void*)attn_kernel,
                        hipFuncAttributeMaxDynamicSharedMemorySize, 147456);
    attn_kernel<<<dim3(512), 512, 147456, stream>>>(q_ws, k_ws, vt_ws, o_ws);
    proj_kernel<<<dim3(MROWS / 64), 256, 0, stream>>>(o_ws, wt_all + 3 * 65536, bp, x, out);
}

// Round 3
// 865.472 us; speedup vs baseline: 3.0864x; 1.1774x over previous
//
#include <hip/hip_runtime.h>
#include <hip/hip_bf16.h>
#include <math.h>

// ---------- types ----------
typedef __attribute__((ext_vector_type(8))) short short8;    // 8 x bf16
typedef __attribute__((ext_vector_type(4))) short short4v;   // 4 x bf16
typedef __attribute__((ext_vector_type(4))) float f32x4;

// B=16, H=W=64 -> N=4096 tokens/batch, C=256, M = B*N = 65536
#define NTOK 4096
#define CDIM 256
#define MROWS 65536

static __device__ __forceinline__ unsigned short f2bf(float f) {
    union { float f; unsigned int u; } v; v.f = f;
    unsigned int u = v.u;
    return (unsigned short)((u + 0x7fffu + ((u >> 16) & 1u)) >> 16);  // RNE
}

static __device__ __forceinline__ unsigned cvt_pk_bf16(float lo, float hi) {
    unsigned r;
    asm("v_cvt_pk_bf16_f32 %0, %1, %2" : "=v"(r) : "v"(lo), "v"(hi));
    return r;
}

static __device__ __forceinline__ f32x4 mfma32(short8 a, short8 b, f32x4 c) {
    return __builtin_amdgcn_mfma_f32_16x16x32_bf16(a, b, c, 0, 0, 0);
}

#if __has_builtin(__builtin_amdgcn_mfma_f32_16x16x16bf16_1k)
static __device__ __forceinline__ f32x4 mfma16(short4v a, short4v b, f32x4 c) {
    return __builtin_amdgcn_mfma_f32_16x16x16bf16_1k(a, b, c, 0, 0, 0);
}
#else
static __device__ __forceinline__ f32x4 mfma16(short4v a, short4v b, f32x4 c) {
    f32x4 d = c;
    asm volatile("v_mfma_f32_16x16x16_bf16 %0, %1, %2, %0" : "+v"(d) : "v"(a), "v"(b));
    return d;
}
#endif

// ---------- kernel 1: transpose + convert weights to bf16 ----------
// wt_all[z][c_out][c_in] = w_z[c_in][c_out]; z=0 (Wq) folds in the 1/16 scale.
__global__ __launch_bounds__(256) void prep_w_kernel(
    const float* __restrict__ wq, const float* __restrict__ wk,
    const float* __restrict__ wv, const float* __restrict__ wp,
    unsigned short* __restrict__ wt_all)
{
    const int o = blockIdx.x;      // c_out
    const int t = threadIdx.x;     // c_in
    const int z = blockIdx.y;
    const float* w = (z == 0) ? wq : (z == 1) ? wk : (z == 2) ? wv : wp;
    const float s = (z == 0) ? 0.0625f : 1.0f;
    wt_all[z * 65536 + o * 256 + t] = f2bf(w[t * 256 + o] * s);
}

// ---------- kernel 2: QKV projections ----------
// One block = 64 token rows = exactly one kv-tile of one batch.
// Outputs: Q row-major bf16; K image [b][tile][kv 64][slot^ (kv&7)] (16B slots);
//          V image [b][tile][c 256][slot ^ (c&7)] (8 k per 16B slot).
__global__ __launch_bounds__(256) void qkv_kernel(
    const float* __restrict__ x,
    const unsigned short* __restrict__ wt_all,
    const float* __restrict__ bq, const float* __restrict__ bk,
    const float* __restrict__ bv,
    unsigned short* __restrict__ q_ws, unsigned short* __restrict__ k_img,
    unsigned short* __restrict__ v_img)
{
    __shared__ unsigned short xs[64 * 256];   // 32 KiB, reused per z
    const int t = threadIdx.x;
    const long m0 = (long)blockIdx.x * 64;
    const int bb = (int)(m0 >> 12);
    const int tile = (int)((m0 & 4095) >> 6);
    const long img_base = ((long)bb * 64 + tile) * 32768;  // bytes

    // stage X tile (fp32 -> bf16) into LDS
    #pragma unroll
    for (int i = 0; i < 16; ++i) {
        int idx = i * 256 + t;
        int row = idx >> 6;
        int c4 = (idx & 63) << 2;
        float4 v = *reinterpret_cast<const float4*>(x + (m0 + row) * CDIM + c4);
        ushort4 pk;
        pk.x = f2bf(v.x); pk.y = f2bf(v.y); pk.z = f2bf(v.z); pk.w = f2bf(v.w);
        *reinterpret_cast<ushort4*>(&xs[row * 256 + c4]) = pk;
    }
    __syncthreads();

    const int wave = t >> 6, lane = t & 63;
    const int lr = lane & 15, lh = lane >> 4;

    short8 a_frag[8];
    #pragma unroll
    for (int kk = 0; kk < 8; ++kk)
        a_frag[kk] = *reinterpret_cast<const short8*>(
            &xs[(wave * 16 + lr) * 256 + kk * 32 + lh * 8]);
    __syncthreads();   // xs free

    for (int z = 0; z < 3; ++z) {
        const unsigned short* wt = wt_all + z * 65536;
        f32x4 acc[16];
        #pragma unroll
        for (int cb = 0; cb < 16; ++cb) acc[cb] = (f32x4)(0.0f);

        for (int kk = 0; kk < 8; ++kk) {
            #pragma unroll
            for (int cb = 0; cb < 16; ++cb) {
                short8 b_frag = *reinterpret_cast<const short8*>(
                    &wt[(cb * 16 + lr) * 256 + kk * 32 + lh * 8]);
                acc[cb] = mfma32(a_frag[kk], b_frag, acc[cb]);
            }
        }

        if (z < 2) {
            const float* bias = (z == 0) ? bq : bk;
            const float bs = (z == 0) ? 0.0625f : 1.0f;
            #pragma unroll
            for (int cb = 0; cb < 16; ++cb) {
                int c = cb * 16 + lr;
                float bb_ = bias[c] * bs;
                #pragma unroll
                for (int r = 0; r < 4; ++r)
                    xs[(wave * 16 + lh * 4 + r) * 256 + c] = f2bf(acc[cb][r] + bb_);
            }
            __syncthreads();
            if (z == 0) {
                char* dst = (char*)(q_ws) + m0 * 512;
                #pragma unroll
                for (int i = 0; i < 8; ++i) {
                    int g = i * 4096 + t * 16;
                    int row = g >> 9, s = (g >> 4) & 31;
                    *reinterpret_cast<short8*>(dst + g) =
                        *reinterpret_cast<const short8*>(&xs[row * 256 + s * 8]);
                }
            } else {
                char* dst = (char*)k_img + img_base;
                #pragma unroll
                for (int i = 0; i < 8; ++i) {
                    int g = i * 4096 + t * 16;
                    int row = g >> 9, sp = (g >> 4) & 31;
                    int s = sp ^ (row & 7);
                    *reinterpret_cast<short8*>(dst + g) =
                        *reinterpret_cast<const short8*>(&xs[row * 256 + s * 8]);
                }
            }
            __syncthreads();
        } else {
            // V: write acc directly into the swizzled transposed image in LDS
            char* xc = (char*)xs;
            #pragma unroll
            for (int cb = 0; cb < 16; ++cb) {
                int c = cb * 16 + lr;
                float bb_ = bv[c];
                #pragma unroll
                for (int r = 0; r < 4; ++r) {
                    int n = wave * 16 + lh * 4 + r;
                    *reinterpret_cast<unsigned short*>(
                        xc + c * 128 + (((n >> 3) ^ (c & 7)) * 16) + (n & 7) * 2)
                        = f2bf(acc[cb][r] + bb_);
                }
            }
            __syncthreads();
            char* dst = (char*)v_img + img_base;
            #pragma unroll
            for (int i = 0; i < 8; ++i) {
                int g = i * 4096 + t * 16;
                *reinterpret_cast<short8*>(dst + g) =
                    *reinterpret_cast<const short8*>(xc + g);
            }
        }
    }
}

// ---------- kernel 3: fused flash attention + output projection + residual ----------
// 256 blocks (16 batches x 16 q-chunks of 256), 8 waves x 32 q rows.
// Swapped QK^T (S^T in regs, in-register softmax), swapped PV via 16x16x16 MFMA.
__global__ __launch_bounds__(512, 2) void attn_kernel(
    const unsigned short* __restrict__ q_ws,
    const unsigned short* __restrict__ k_img,
    const unsigned short* __restrict__ v_img,
    const unsigned short* __restrict__ wpt,
    const float* __restrict__ bp,
    const float* __restrict__ x,
    float* __restrict__ out)
{
    extern __shared__ char smem[];
    char* ksb = smem;             // 2 x 32KB K tiles
    char* vsb = smem + 65536;     // 2 x 32KB V tiles
    const int t = threadIdx.x;
    const int wave = t >> 6, lane = t & 63;
    const int lr = lane & 15, lh = lane >> 4;

    // XCD-aware mapping: batch b's 16 blocks all live on XCD b>>1
    const int bid = blockIdx.x;
    const int xcd = bid & 7, ii = bid >> 3;
    const int b = (xcd << 1) | (ii & 1);
    const int qc = ii >> 1;
    const long qbase = (long)b * NTOK + qc * 256 + wave * 32;

    const char* kg = (const char*)k_img + ((long)b * 64) * 32768;
    const char* vg = (const char*)v_img + ((long)b * 64) * 32768;

    // Q fragments, resident (scale pre-folded)
    short8 qf[2][8];
    #pragma unroll
    for (int qb = 0; qb < 2; ++qb)
        #pragma unroll
        for (int kk = 0; kk < 8; ++kk)
            qf[qb][kk] = *reinterpret_cast<const short8*>(
                &q_ws[(qbase + qb * 16 + lr) * 256 + kk * 32 + lh * 8]);

    f32x4 acc[2][16];
    #pragma unroll
    for (int qb = 0; qb < 2; ++qb)
        #pragma unroll
        for (int cb = 0; cb < 16; ++cb) acc[qb][cb] = (f32x4)(0.0f);
    float m_run[2] = {-INFINITY, -INFINITY};
    float l_run[2] = {0.f, 0.f};

    short8 sreg[4];
    auto gloadK = [&](int tt) {
        const char* s = kg + (long)tt * 32768 + wave * 4096 + lane * 16;
        #pragma unroll
        for (int i = 0; i < 4; ++i)
            sreg[i] = *reinterpret_cast<const short8*>(s + i * 1024);
    };
    auto gloadV = [&](int tt) {
        const char* s = vg + (long)tt * 32768 + wave * 4096 + lane * 16;
        #pragma unroll
        for (int i = 0; i < 4; ++i)
            sreg[i] = *reinterpret_cast<const short8*>(s + i * 1024);
    };
    auto putK = [&](int nb) {
        char* d = ksb + nb * 32768 + wave * 4096 + lane * 16;
        #pragma unroll
        for (int i = 0; i < 4; ++i)
            *reinterpret_cast<short8*>(d + i * 1024) = sreg[i];
    };
    auto putV = [&](int nb) {
        char* d = vsb + nb * 32768 + wave * 4096 + lane * 16;
        #pragma unroll
        for (int i = 0; i < 4; ++i)
            *reinterpret_cast<short8*>(d + i * 1024) = sreg[i];
    };

    auto do_half = [&](const char* kb, const char* vb, int h) {
        // ---- QK^T (swapped): S^T[k 32][q 32] ----
        f32x4 s[2][2];   // [qb][kvb]
        s[0][0] = (f32x4)(0.0f); s[0][1] = (f32x4)(0.0f);
        s[1][0] = (f32x4)(0.0f); s[1][1] = (f32x4)(0.0f);
        __builtin_amdgcn_s_setprio(1);
        #pragma unroll
        for (int kk = 0; kk < 8; ++kk) {
            int slot = ((kk * 4 + lh) ^ (lr & 7)) * 16;
            short8 kf0 = *reinterpret_cast<const short8*>(kb + (h * 32 + lr) * 512 + slot);
            short8 kf1 = *reinterpret_cast<const short8*>(kb + (h * 32 + 16 + lr) * 512 + slot);
            s[0][0] = mfma32(kf0, qf[0][kk], s[0][0]);
            s[1][0] = mfma32(kf0, qf[1][kk], s[1][0]);
            s[0][1] = mfma32(kf1, qf[0][kk], s[0][1]);
            s[1][1] = mfma32(kf1, qf[1][kk], s[1][1]);
        }
        __builtin_amdgcn_s_setprio(0);

        // ---- in-register online softmax (lane owns q = qb*16+lr; k = kvb*16+lh*4+r) ----
        short4v pb[2][2];
        #pragma unroll
        for (int qb = 0; qb < 2; ++qb) {
            float mt = fmaxf(fmaxf(fmaxf(s[qb][0][0], s[qb][0][1]), fmaxf(s[qb][0][2], s[qb][0][3])),
                             fmaxf(fmaxf(s[qb][1][0], s[qb][1][1]), fmaxf(s[qb][1][2], s[qb][1][3])));
            mt = fmaxf(mt, __shfl_xor(mt, 16));
            mt = fmaxf(mt, __shfl_xor(mt, 32));
            if (!__all(mt <= m_run[qb] + 8.0f)) {       // defer-max (T13)
                float mn = fmaxf(m_run[qb], mt);
                float a = __expf(m_run[qb] - mn);
                l_run[qb] *= a;
                #pragma unroll
                for (int cb = 0; cb < 16; ++cb) {
                    acc[qb][cb][0] *= a; acc[qb][cb][1] *= a;
                    acc[qb][cb][2] *= a; acc[qb][cb][3] *= a;
                }
                m_run[qb] = mn;
            }
            float e0 = __expf(s[qb][0][0] - m_run[qb]);
            float e1 = __expf(s[qb][0][1] - m_run[qb]);
            float e2 = __expf(s[qb][0][2] - m_run[qb]);
            float e3 = __expf(s[qb][0][3] - m_run[qb]);
            float e4 = __expf(s[qb][1][0] - m_run[qb]);
            float e5 = __expf(s[qb][1][1] - m_run[qb]);
            float e6 = __expf(s[qb][1][2] - m_run[qb]);
            float e7 = __expf(s[qb][1][3] - m_run[qb]);
            float rs = ((e0 + e1) + (e2 + e3)) + ((e4 + e5) + (e6 + e7));
            rs += __shfl_xor(rs, 16);
            rs += __shfl_xor(rs, 32);
            l_run[qb] += rs;
            union { unsigned u[2]; short4v v; } p0, p1;
            p0.u[0] = cvt_pk_bf16(e0, e1); p0.u[1] = cvt_pk_bf16(e2, e3);
            p1.u[0] = cvt_pk_bf16(e4, e5); p1.u[1] = cvt_pk_bf16(e6, e7);
            pb[qb][0] = p0.v; pb[qb][1] = p1.v;
        }

        // ---- PV (swapped, 16x16x16): acc[c][q] += V^T[c][k] * P^T[k][q] ----
        __builtin_amdgcn_s_setprio(1);
        #pragma unroll
        for (int cb = 0; cb < 16; ++cb) {
            int c = cb * 16 + lr;
            const char* rowp = vb + c * 128 + (lh & 1) * 8;
            int swz = c & 7;
            short4v va0 = *reinterpret_cast<const short4v*>(
                rowp + (((h * 4 + (lh >> 1)) ^ swz) * 16));
            short4v va1 = *reinterpret_cast<const short4v*>(
                rowp + (((h * 4 + 2 + (lh >> 1)) ^ swz) * 16));
            acc[0][cb] = mfma16(va0, pb[0][0], acc[0][cb]);
            acc[1][cb] = mfma16(va0, pb[1][0], acc[1][cb]);
            acc[0][cb] = mfma16(va1, pb[0][1], acc[0][cb]);
            acc[1][cb] = mfma16(va1, pb[1][1], acc[1][cb]);
        }
        __builtin_amdgcn_s_setprio(0);
    };

    // prologue: tile 0
    gloadK(0); putK(0);
    gloadV(0); putV(0);
    __syncthreads();

    for (int tt = 0; tt < 64; ++tt) {
        const int buf = tt & 1, nb = buf ^ 1;
        const char* kb = ksb + buf * 32768;
        const char* vb = vsb + buf * 32768;
        if (tt < 63) gloadK(tt + 1);
        do_half(kb, vb, 0);
        if (tt < 63) { putK(nb); gloadV(tt + 1); }
        do_half(kb, vb, 1);
        if (tt < 63) putV(nb);
        __syncthreads();
    }

    // ---- epilogue: O^T -> per-wave LDS transpose (swizzled) ----
    float inv[2] = {1.0f / l_run[0], 1.0f / l_run[1]};
    char* ot = smem + wave * 16384;   // [32 q][512B], slot ^= q&7
    #pragma unroll
    for (int qb = 0; qb < 2; ++qb) {
        int q = qb * 16 + lr;
        int swq = q & 7;
        #pragma unroll
        for (int cb = 0; cb < 16; ++cb) {
            #pragma unroll
            for (int r = 0; r < 4; ++r) {
                int c = cb * 16 + lh * 4 + r;
                *reinterpret_cast<unsigned short*>(
                    ot + q * 512 + (((c >> 3) ^ swq) * 16) + (c & 7) * 2)
                    = f2bf(acc[qb][cb][r] * inv[qb]);
            }
        }
    }

    // ---- fused projection: OUT = O @ Wp + bp + x ----
    f32x4 po[2][16];
    #pragma unroll
    for (int qb = 0; qb < 2; ++qb)
        #pragma unroll
        for (int cb = 0; cb < 16; ++cb) po[qb][cb] = (f32x4)(0.0f);

    for (int kk = 0; kk < 8; ++kk) {
        int slot = (kk * 4 + lh);
        short8 a0 = *reinterpret_cast<const short8*>(
            ot + (0 * 16 + lr) * 512 + ((slot ^ (lr & 7)) * 16));
        short8 a1 = *reinterpret_cast<const short8*>(
            ot + (1 * 16 + lr) * 512 + ((slot ^ (lr & 7)) * 16));
        #pragma unroll
        for (int cb = 0; cb < 16; ++cb) {
            short8 bf_ = *reinterpret_cast<const short8*>(
                &wpt[(cb * 16 + lr) * 256 + kk * 32 + lh * 8]);
            po[0][cb] = mfma32(a0, bf_, po[0][cb]);
            po[1][cb] = mfma32(a1, bf_, po[1][cb]);
        }
    }

    #pragma unroll
    for (int qb = 0; qb < 2; ++qb) {
        #pragma unroll
        for (int cb = 0; cb < 16; ++cb) {
            int c = cb * 16 + lr;
            float bias = bp[c];
            #pragma unroll
            for (int r = 0; r < 4; ++r) {
                long row = qbase + qb * 16 + lh * 4 + r;
                out[row * 256 + c] = po[qb][cb][r] + bias + x[row * 256 + c];
            }
        }
    }
}

extern "C" void kernel_launch(void* const* d_in, const int* in_sizes, int n_in,
                              void* d_out, int out_size, void* d_ws, size_t ws_size,
                              hipStream_t stream) {
    const float* x  = (const float*)d_in[0];
    const float* wq = (const float*)d_in[1];
    const float* bq = (const float*)d_in[2];
    const float* wk = (const float*)d_in[3];
    const float* bk = (const float*)d_in[4];
    const float* wv = (const float*)d_in[5];
    const float* bv = (const float*)d_in[6];
    const float* wp = (const float*)d_in[7];
    const float* bp = (const float*)d_in[8];
    float* out = (float*)d_out;

    char* ws = (char*)d_ws;
    unsigned short* wt_all = (unsigned short*)ws;               // 512 KiB
    unsigned short* q_ws   = (unsigned short*)(ws + 524288);    // 32 MiB
    unsigned short* k_img  = q_ws + (size_t)MROWS * CDIM;       // 32 MiB
    unsigned short* v_img  = k_img + (size_t)MROWS * CDIM;      // 32 MiB

    prep_w_kernel<<<dim3(256, 4), 256, 0, stream>>>(wq, wk, wv, wp, wt_all);
    qkv_kernel<<<dim3(MROWS / 64), 256, 0, stream>>>(x, wt_all, bq, bk, bv,
                                                     q_ws, k_img, v_img);
    hipFuncSetAttribute((const void*)attn_kernel,
                        hipFuncAttributeMaxDynamicSharedMemorySize, 131072);
    attn_kernel<<<dim3(256), 512, 131072, stream>>>(q_ws, k_img, v_img,
                                                    wt_all + 3 * 65536, bp, x, out);
}

// Round 4
// 464.583 us; speedup vs baseline: 5.7497x; 1.8629x over previous
//
#include <hip/hip_runtime.h>
#include <hip/hip_bf16.h>
#include <math.h>

// ---------- types ----------
typedef __attribute__((ext_vector_type(8))) short short8;    // 8 x bf16
typedef __attribute__((ext_vector_type(4))) short short4v;   // 4 x bf16
typedef __attribute__((ext_vector_type(4))) float f32x4;

// B=16, H=W=64 -> N=4096 tokens/batch, C=256, M = B*N = 65536
#define NTOK 4096
#define CDIM 256
#define MROWS 65536

static __device__ __forceinline__ unsigned short f2bf(float f) {
    union { float f; unsigned int u; } v; v.f = f;
    unsigned int u = v.u;
    return (unsigned short)((u + 0x7fffu + ((u >> 16) & 1u)) >> 16);  // RNE
}

static __device__ __forceinline__ unsigned cvt_pk_bf16(float lo, float hi) {
    unsigned r;
    asm("v_cvt_pk_bf16_f32 %0, %1, %2" : "=v"(r) : "v"(lo), "v"(hi));
    return r;
}

static __device__ __forceinline__ f32x4 mfma32(short8 a, short8 b, f32x4 c) {
    return __builtin_amdgcn_mfma_f32_16x16x32_bf16(a, b, c, 0, 0, 0);
}

#if __has_builtin(__builtin_amdgcn_mfma_f32_16x16x16bf16_1k)
static __device__ __forceinline__ f32x4 mfma16(short4v a, short4v b, f32x4 c) {
    return __builtin_amdgcn_mfma_f32_16x16x16bf16_1k(a, b, c, 0, 0, 0);
}
#else
static __device__ __forceinline__ f32x4 mfma16(short4v a, short4v b, f32x4 c) {
    f32x4 d = c;
    asm volatile("v_mfma_f32_16x16x16_bf16 %0, %1, %2, %0" : "+v"(d) : "v"(a), "v"(b));
    return d;
}
#endif

// ---------- kernel 1: transpose + convert weights to bf16 ----------
// wt_all[z][c_out][c_in] = w_z[c_in][c_out]; z=0 (Wq) folds in the 1/16 scale.
__global__ __launch_bounds__(256) void prep_w_kernel(
    const float* __restrict__ wq, const float* __restrict__ wk,
    const float* __restrict__ wv, const float* __restrict__ wp,
    unsigned short* __restrict__ wt_all)
{
    const int o = blockIdx.x;      // c_out
    const int t = threadIdx.x;     // c_in
    const int z = blockIdx.y;
    const float* w = (z == 0) ? wq : (z == 1) ? wk : (z == 2) ? wv : wp;
    const float s = (z == 0) ? 0.0625f : 1.0f;
    wt_all[z * 65536 + o * 256 + t] = f2bf(w[t * 256 + o] * s);
}

// ---------- kernel 2: QKV projections (weights streamed through LDS) ----------
// One block = 64 token rows = one kv-tile of one batch. Weight matrix streamed
// in 12 chunks (3 z x 4 chunks of 64 c_out), reg-double-buffered into one
// 32KB swizzled LDS buffer. Results staged in the X LDS buffer, then written
// via coalesced image writers.
__global__ __launch_bounds__(256) void qkv_kernel(
    const float* __restrict__ x,
    const unsigned short* __restrict__ wt_all,
    const float* __restrict__ bq, const float* __restrict__ bk,
    const float* __restrict__ bv,
    unsigned short* __restrict__ q_ws, unsigned short* __restrict__ k_img,
    unsigned short* __restrict__ v_img)
{
    __shared__ unsigned short xs[64 * 256];   // 32 KB: X tile, then result staging
    __shared__ char wchunk[32768];            // 64 c_out x 512B (swizzled 16B slots)
    const int t = threadIdx.x;
    const long m0 = (long)blockIdx.x * 64;
    const int bb = (int)(m0 >> 12);
    const int tile = (int)((m0 & 4095) >> 6);
    const long img_base = ((long)bb * 64 + tile) * 32768;  // bytes

    const int wave = t >> 6, lane = t & 63;
    const int lr = lane & 15, lh = lane >> 4;

    // weight chunk staging: global -> regs -> swizzled LDS
    short8 wreg[8];
    auto wload = [&](int j) {   // chunk j in 0..11 (z = j>>2, cc = j&3)
        const char* src = (const char*)wt_all + (long)j * 32768 + t * 16;
        #pragma unroll
        for (int i = 0; i < 8; ++i)
            wreg[i] = *reinterpret_cast<const short8*>(src + i * 4096);
    };
    auto wstore = [&]() {
        #pragma unroll
        for (int i = 0; i < 8; ++i) {
            int g = i * 4096 + t * 16;
            int row = g >> 9, slot = (g >> 4) & 31;
            *reinterpret_cast<short8*>(
                wchunk + row * 512 + ((slot ^ (row & 7)) * 16)) = wreg[i];
        }
    };

    wload(0);   // chunk 0 loads in flight under X staging

    // stage X tile (fp32 -> bf16) into LDS
    #pragma unroll
    for (int i = 0; i < 16; ++i) {
        int idx = i * 256 + t;
        int row = idx >> 6;
        int c4 = (idx & 63) << 2;
        float4 v = *reinterpret_cast<const float4*>(x + (m0 + row) * CDIM + c4);
        ushort4 pk;
        pk.x = f2bf(v.x); pk.y = f2bf(v.y); pk.z = f2bf(v.z); pk.w = f2bf(v.w);
        *reinterpret_cast<ushort4*>(&xs[row * 256 + c4]) = pk;
    }
    __syncthreads();

    short8 a_frag[8];
    #pragma unroll
    for (int kk = 0; kk < 8; ++kk)
        a_frag[kk] = *reinterpret_cast<const short8*>(
            &xs[(wave * 16 + lr) * 256 + kk * 32 + lh * 8]);

    wstore();           // chunk 0 -> LDS (vmcnt waited by compiler)
    __syncthreads();    // wchunk0 ready; all waves' a_frags loaded (own rows)
    wload(1);

    for (int j = 0; j < 12; ++j) {
        const int z = j >> 2, cc = j & 3;

        f32x4 acc[4];
        #pragma unroll
        for (int cb = 0; cb < 4; ++cb) acc[cb] = (f32x4)(0.0f);

        __builtin_amdgcn_s_setprio(1);
        #pragma unroll
        for (int kk = 0; kk < 8; ++kk) {
            #pragma unroll
            for (int cb = 0; cb < 4; ++cb) {
                short8 b_frag = *reinterpret_cast<const short8*>(
                    wchunk + (cb * 16 + lr) * 512 + (((kk * 4 + lh) ^ (lr & 7)) * 16));
                acc[cb] = mfma32(a_frag[kk], b_frag, acc[cb]);
            }
        }
        __builtin_amdgcn_s_setprio(0);

        // epilogue: acc -> xs staging
        if (z < 2) {
            const float* bias = (z == 0) ? bq : bk;
            const float bs = (z == 0) ? 0.0625f : 1.0f;
            #pragma unroll
            for (int cb = 0; cb < 4; ++cb) {
                int c = cc * 64 + cb * 16 + lr;
                float bb_ = bias[c] * bs;
                #pragma unroll
                for (int r = 0; r < 4; ++r)
                    xs[(wave * 16 + lh * 4 + r) * 256 + c] = f2bf(acc[cb][r] + bb_);
            }
        } else {
            // V: write into swizzled transposed image layout in xs
            char* xc = (char*)xs;
            #pragma unroll
            for (int cb = 0; cb < 4; ++cb) {
                int c = cc * 64 + cb * 16 + lr;
                float bb_ = bv[c];
                #pragma unroll
                for (int r = 0; r < 4; ++r) {
                    int n = wave * 16 + lh * 4 + r;
                    *reinterpret_cast<unsigned short*>(
                        xc + c * 128 + (((n >> 3) ^ (c & 7)) * 16) + (n & 7) * 2)
                        = f2bf(acc[cb][r] + bb_);
                }
            }
        }
        __syncthreads();   // wchunk free for rewrite; xs complete when cc==3

        if (cc == 3) {
            // image write for projection z (reads xs, disjoint from wchunk)
            if (z == 0) {
                char* dst = (char*)q_ws + m0 * 512;
                const char* src = (const char*)xs;
                #pragma unroll
                for (int i = 0; i < 8; ++i) {
                    int g = i * 4096 + t * 16;
                    *reinterpret_cast<short8*>(dst + g) =
                        *reinterpret_cast<const short8*>(src + g);
                }
            } else if (z == 1) {
                char* dst = (char*)k_img + img_base;
                #pragma unroll
                for (int i = 0; i < 8; ++i) {
                    int g = i * 4096 + t * 16;
                    int row = g >> 9, sp = (g >> 4) & 31;
                    int s = sp ^ (row & 7);
                    *reinterpret_cast<short8*>(dst + g) =
                        *reinterpret_cast<const short8*>(&xs[row * 256 + s * 8]);
                }
            } else {
                char* dst = (char*)v_img + img_base;
                const char* src = (const char*)xs;
                #pragma unroll
                for (int i = 0; i < 8; ++i) {
                    int g = i * 4096 + t * 16;
                    *reinterpret_cast<short8*>(dst + g) =
                        *reinterpret_cast<const short8*>(src + g);
                }
            }
        }

        if (j < 11) wstore();        // chunk j+1 regs -> LDS
        if (j < 10) wload(j + 2);    // issue chunk j+2 global loads
        __syncthreads();             // wchunk j+1 visible; xs readers done
    }
}

// ---------- kernel 3: fused flash attention + output projection + residual ----------
// 256 blocks (16 batches x 16 q-chunks of 256), 8 waves x 32 q rows.
// Swapped QK^T (S^T in regs, in-register softmax), swapped PV via 16x16x16 MFMA.
__global__ __launch_bounds__(512, 2) void attn_kernel(
    const unsigned short* __restrict__ q_ws,
    const unsigned short* __restrict__ k_img,
    const unsigned short* __restrict__ v_img,
    const unsigned short* __restrict__ wpt,
    const float* __restrict__ bp,
    const float* __restrict__ x,
    float* __restrict__ out)
{
    extern __shared__ char smem[];
    char* ksb = smem;             // 2 x 32KB K tiles
    char* vsb = smem + 65536;     // 2 x 32KB V tiles
    const int t = threadIdx.x;
    const int wave = t >> 6, lane = t & 63;
    const int lr = lane & 15, lh = lane >> 4;

    // XCD-aware mapping: batch b's 16 blocks all live on XCD b>>1
    const int bid = blockIdx.x;
    const int xcd = bid & 7, ii = bid >> 3;
    const int b = (xcd << 1) | (ii & 1);
    const int qc = ii >> 1;
    const long qbase = (long)b * NTOK + qc * 256 + wave * 32;

    const char* kg = (const char*)k_img + ((long)b * 64) * 32768;
    const char* vg = (const char*)v_img + ((long)b * 64) * 32768;

    // Q fragments, resident (scale pre-folded)
    short8 qf[2][8];
    #pragma unroll
    for (int qb = 0; qb < 2; ++qb)
        #pragma unroll
        for (int kk = 0; kk < 8; ++kk)
            qf[qb][kk] = *reinterpret_cast<const short8*>(
                &q_ws[(qbase + qb * 16 + lr) * 256 + kk * 32 + lh * 8]);

    f32x4 acc[2][16];
    #pragma unroll
    for (int qb = 0; qb < 2; ++qb)
        #pragma unroll
        for (int cb = 0; cb < 16; ++cb) acc[qb][cb] = (f32x4)(0.0f);
    float m_run[2] = {-INFINITY, -INFINITY};
    float l_run[2] = {0.f, 0.f};

    short8 sreg[4];
    auto gloadK = [&](int tt) {
        const char* s = kg + (long)tt * 32768 + wave * 4096 + lane * 16;
        #pragma unroll
        for (int i = 0; i < 4; ++i)
            sreg[i] = *reinterpret_cast<const short8*>(s + i * 1024);
    };
    auto gloadV = [&](int tt) {
        const char* s = vg + (long)tt * 32768 + wave * 4096 + lane * 16;
        #pragma unroll
        for (int i = 0; i < 4; ++i)
            sreg[i] = *reinterpret_cast<const short8*>(s + i * 1024);
    };
    auto putK = [&](int nb) {
        char* d = ksb + nb * 32768 + wave * 4096 + lane * 16;
        #pragma unroll
        for (int i = 0; i < 4; ++i)
            *reinterpret_cast<short8*>(d + i * 1024) = sreg[i];
    };
    auto putV = [&](int nb) {
        char* d = vsb + nb * 32768 + wave * 4096 + lane * 16;
        #pragma unroll
        for (int i = 0; i < 4; ++i)
            *reinterpret_cast<short8*>(d + i * 1024) = sreg[i];
    };

    auto do_half = [&](const char* kb, const char* vb, int h) {
        // ---- QK^T (swapped): S^T[k 32][q 32] ----
        f32x4 s[2][2];   // [qb][kvb]
        s[0][0] = (f32x4)(0.0f); s[0][1] = (f32x4)(0.0f);
        s[1][0] = (f32x4)(0.0f); s[1][1] = (f32x4)(0.0f);
        __builtin_amdgcn_s_setprio(1);
        #pragma unroll
        for (int kk = 0; kk < 8; ++kk) {
            int slot = ((kk * 4 + lh) ^ (lr & 7)) * 16;
            short8 kf0 = *reinterpret_cast<const short8*>(kb + (h * 32 + lr) * 512 + slot);
            short8 kf1 = *reinterpret_cast<const short8*>(kb + (h * 32 + 16 + lr) * 512 + slot);
            s[0][0] = mfma32(kf0, qf[0][kk], s[0][0]);
            s[1][0] = mfma32(kf0, qf[1][kk], s[1][0]);
            s[0][1] = mfma32(kf1, qf[0][kk], s[0][1]);
            s[1][1] = mfma32(kf1, qf[1][kk], s[1][1]);
        }
        __builtin_amdgcn_s_setprio(0);

        // ---- in-register online softmax (lane owns q = qb*16+lr; k = kvb*16+lh*4+r) ----
        short4v pb[2][2];
        #pragma unroll
        for (int qb = 0; qb < 2; ++qb) {
            float mt = fmaxf(fmaxf(fmaxf(s[qb][0][0], s[qb][0][1]), fmaxf(s[qb][0][2], s[qb][0][3])),
                             fmaxf(fmaxf(s[qb][1][0], s[qb][1][1]), fmaxf(s[qb][1][2], s[qb][1][3])));
            mt = fmaxf(mt, __shfl_xor(mt, 16));
            mt = fmaxf(mt, __shfl_xor(mt, 32));
            if (!__all(mt <= m_run[qb] + 8.0f)) {       // defer-max (T13)
                float mn = fmaxf(m_run[qb], mt);
                float a = __expf(m_run[qb] - mn);
                l_run[qb] *= a;
                #pragma unroll
                for (int cb = 0; cb < 16; ++cb) {
                    acc[qb][cb][0] *= a; acc[qb][cb][1] *= a;
                    acc[qb][cb][2] *= a; acc[qb][cb][3] *= a;
                }
                m_run[qb] = mn;
            }
            float e0 = __expf(s[qb][0][0] - m_run[qb]);
            float e1 = __expf(s[qb][0][1] - m_run[qb]);
            float e2 = __expf(s[qb][0][2] - m_run[qb]);
            float e3 = __expf(s[qb][0][3] - m_run[qb]);
            float e4 = __expf(s[qb][1][0] - m_run[qb]);
            float e5 = __expf(s[qb][1][1] - m_run[qb]);
            float e6 = __expf(s[qb][1][2] - m_run[qb]);
            float e7 = __expf(s[qb][1][3] - m_run[qb]);
            float rs = ((e0 + e1) + (e2 + e3)) + ((e4 + e5) + (e6 + e7));
            rs += __shfl_xor(rs, 16);
            rs += __shfl_xor(rs, 32);
            l_run[qb] += rs;
            union { unsigned u[2]; short4v v; } p0, p1;
            p0.u[0] = cvt_pk_bf16(e0, e1); p0.u[1] = cvt_pk_bf16(e2, e3);
            p1.u[0] = cvt_pk_bf16(e4, e5); p1.u[1] = cvt_pk_bf16(e6, e7);
            pb[qb][0] = p0.v; pb[qb][1] = p1.v;
        }

        // ---- PV (swapped, 16x16x16): acc[c][q] += V^T[c][k] * P^T[k][q] ----
        __builtin_amdgcn_s_setprio(1);
        #pragma unroll
        for (int cb = 0; cb < 16; ++cb) {
            int c = cb * 16 + lr;
            const char* rowp = vb + c * 128 + (lh & 1) * 8;
            int swz = c & 7;
            short4v va0 = *reinterpret_cast<const short4v*>(
                rowp + (((h * 4 + (lh >> 1)) ^ swz) * 16));
            short4v va1 = *reinterpret_cast<const short4v*>(
                rowp + (((h * 4 + 2 + (lh >> 1)) ^ swz) * 16));
            acc[0][cb] = mfma16(va0, pb[0][0], acc[0][cb]);
            acc[1][cb] = mfma16(va0, pb[1][0], acc[1][cb]);
            acc[0][cb] = mfma16(va1, pb[0][1], acc[0][cb]);
            acc[1][cb] = mfma16(va1, pb[1][1], acc[1][cb]);
        }
        __builtin_amdgcn_s_setprio(0);
    };

    // prologue: tile 0
    gloadK(0); putK(0);
    gloadV(0); putV(0);
    __syncthreads();

    for (int tt = 0; tt < 64; ++tt) {
        const int buf = tt & 1, nb = buf ^ 1;
        const char* kb = ksb + buf * 32768;
        const char* vb = vsb + buf * 32768;
        if (tt < 63) gloadK(tt + 1);
        do_half(kb, vb, 0);
        if (tt < 63) { putK(nb); gloadV(tt + 1); }
        do_half(kb, vb, 1);
        if (tt < 63) putV(nb);
        __syncthreads();
    }

    // ---- epilogue: O^T -> per-wave LDS transpose (swizzled) ----
    float inv[2] = {1.0f / l_run[0], 1.0f / l_run[1]};
    char* ot = smem + wave * 16384;   // [32 q][512B], slot ^= q&7
    #pragma unroll
    for (int qb = 0; qb < 2; ++qb) {
        int q = qb * 16 + lr;
        int swq = q & 7;
        #pragma unroll
        for (int cb = 0; cb < 16; ++cb) {
            #pragma unroll
            for (int r = 0; r < 4; ++r) {
                int c = cb * 16 + lh * 4 + r;
                *reinterpret_cast<unsigned short*>(
                    ot + q * 512 + (((c >> 3) ^ swq) * 16) + (c & 7) * 2)
                    = f2bf(acc[qb][cb][r] * inv[qb]);
            }
        }
    }

    // ---- fused projection: OUT = O @ Wp + bp + x ----
    f32x4 po[2][16];
    #pragma unroll
    for (int qb = 0; qb < 2; ++qb)
        #pragma unroll
        for (int cb = 0; cb < 16; ++cb) po[qb][cb] = (f32x4)(0.0f);

    for (int kk = 0; kk < 8; ++kk) {
        int slot = (kk * 4 + lh);
        short8 a0 = *reinterpret_cast<const short8*>(
            ot + (0 * 16 + lr) * 512 + ((slot ^ (lr & 7)) * 16));
        short8 a1 = *reinterpret_cast<const short8*>(
            ot + (1 * 16 + lr) * 512 + ((slot ^ (lr & 7)) * 16));
        #pragma unroll
        for (int cb = 0; cb < 16; ++cb) {
            short8 bf_ = *reinterpret_cast<const short8*>(
                &wpt[(cb * 16 + lr) * 256 + kk * 32 + lh * 8]);
            po[0][cb] = mfma32(a0, bf_, po[0][cb]);
            po[1][cb] = mfma32(a1, bf_, po[1][cb]);
        }
    }

    #pragma unroll
    for (int qb = 0; qb < 2; ++qb) {
        #pragma unroll
        for (int cb = 0; cb < 16; ++cb) {
            int c = cb * 16 + lr;
            float bias = bp[c];
            #pragma unroll
            for (int r = 0; r < 4; ++r) {
                long row = qbase + qb * 16 + lh * 4 + r;
                out[row * 256 + c] = po[qb][cb][r] + bias + x[row * 256 + c];
            }
        }
    }
}

extern "C" void kernel_launch(void* const* d_in, const int* in_sizes, int n_in,
                              void* d_out, int out_size, void* d_ws, size_t ws_size,
                              hipStream_t stream) {
    const float* x  = (const float*)d_in[0];
    const float* wq = (const float*)d_in[1];
    const float* bq = (const float*)d_in[2];
    const float* wk = (const float*)d_in[3];
    const float* bk = (const float*)d_in[4];
    const float* wv = (const float*)d_in[5];
    const float* bv = (const float*)d_in[6];
    const float* wp = (const float*)d_in[7];
    const float* bp = (const float*)d_in[8];
    float* out = (float*)d_out;

    char* ws = (char*)d_ws;
    unsigned short* wt_all = (unsigned short*)ws;               // 512 KiB
    unsigned short* q_ws   = (unsigned short*)(ws + 524288);    // 32 MiB
    unsigned short* k_img  = q_ws + (size_t)MROWS * CDIM;       // 32 MiB
    unsigned short* v_img  = k_img + (size_t)MROWS * CDIM;      // 32 MiB

    prep_w_kernel<<<dim3(256, 4), 256, 0, stream>>>(wq, wk, wv, wp, wt_all);
    qkv_kernel<<<dim3(MROWS / 64), 256, 0, stream>>>(x, wt_all, bq, bk, bv,
                                                     q_ws, k_img, v_img);
    hipFuncSetAttribute((const void*)attn_kernel,
                        hipFuncAttributeMaxDynamicSharedMemorySize, 131072);
    attn_kernel<<<dim3(256), 512, 131072, stream>>>(q_ws, k_img, v_img,
                                                    wt_all + 3 * 65536, bp, x, out);
}

// Round 5
// 373.556 us; speedup vs baseline: 7.1508x; 1.2437x over previous
//
#include <hip/hip_runtime.h>
#include <hip/hip_bf16.h>
#include <math.h>

// ---------- types ----------
typedef __attribute__((ext_vector_type(8))) short short8;    // 8 x bf16
typedef __attribute__((ext_vector_type(4))) float f32x4;
typedef __attribute__((ext_vector_type(16))) float f32x16;

// B=16, H=W=64 -> N=4096 tokens/batch, C=256, M = B*N = 65536
#define NTOK 4096
#define CDIM 256
#define MROWS 65536

static __device__ __forceinline__ unsigned short f2bf(float f) {
    union { float f; unsigned int u; } v; v.f = f;
    unsigned int u = v.u;
    return (unsigned short)((u + 0x7fffu + ((u >> 16) & 1u)) >> 16);  // RNE
}

static __device__ __forceinline__ unsigned cvt_pk_bf16(float lo, float hi) {
    unsigned r;
    asm("v_cvt_pk_bf16_f32 %0, %1, %2" : "=v"(r) : "v"(lo), "v"(hi));
    return r;
}

static __device__ __forceinline__ f32x4 mfma32(short8 a, short8 b, f32x4 c) {
    return __builtin_amdgcn_mfma_f32_16x16x32_bf16(a, b, c, 0, 0, 0);
}

static __device__ __forceinline__ f32x16 mfma32x32(short8 a, short8 b, f32x16 c) {
    return __builtin_amdgcn_mfma_f32_32x32x16_bf16(a, b, c, 0, 0, 0);
}

// async global -> LDS DMA, 16B per lane (dst = wave-uniform base + lane*16)
static __device__ __forceinline__ void ldsdma16(char* l, const char* g) {
    __builtin_amdgcn_global_load_lds(
        (const __attribute__((address_space(1))) unsigned int*)g,
        (__attribute__((address_space(3))) unsigned int*)l,
        16, 0, 0);
}

// ---------- kernel 1: transpose + convert weights to bf16 ----------
// wt_all[z][c_out][c_in] = w_z[c_in][c_out]; z=0 (Wq) folds in the 1/16 scale.
__global__ __launch_bounds__(256) void prep_w_kernel(
    const float* __restrict__ wq, const float* __restrict__ wk,
    const float* __restrict__ wv, const float* __restrict__ wp,
    unsigned short* __restrict__ wt_all)
{
    const int o = blockIdx.x;      // c_out
    const int t = threadIdx.x;     // c_in
    const int z = blockIdx.y;
    const float* w = (z == 0) ? wq : (z == 1) ? wk : (z == 2) ? wv : wp;
    const float s = (z == 0) ? 0.0625f : 1.0f;
    wt_all[z * 65536 + o * 256 + t] = f2bf(w[t * 256 + o] * s);
}

// ---------- kernel 2: QKV projections (weights streamed through LDS) ----------
__global__ __launch_bounds__(256) void qkv_kernel(
    const float* __restrict__ x,
    const unsigned short* __restrict__ wt_all,
    const float* __restrict__ bq, const float* __restrict__ bk,
    const float* __restrict__ bv,
    unsigned short* __restrict__ q_ws, unsigned short* __restrict__ k_img,
    unsigned short* __restrict__ v_img)
{
    __shared__ unsigned short xs[64 * 256];   // 32 KB: X tile, then result staging
    __shared__ char wchunk[32768];            // 64 c_out x 512B (swizzled 16B slots)
    const int t = threadIdx.x;
    const long m0 = (long)blockIdx.x * 64;
    const int bb = (int)(m0 >> 12);
    const int tile = (int)((m0 & 4095) >> 6);
    const long img_base = ((long)bb * 64 + tile) * 32768;  // bytes

    const int wave = t >> 6, lane = t & 63;
    const int lr = lane & 15, lh = lane >> 4;

    // weight chunk staging: global -> regs -> swizzled LDS
    short8 wreg[8];
    auto wload = [&](int j) {   // chunk j in 0..11 (z = j>>2, cc = j&3)
        const char* src = (const char*)wt_all + (long)j * 32768 + t * 16;
        #pragma unroll
        for (int i = 0; i < 8; ++i)
            wreg[i] = *reinterpret_cast<const short8*>(src + i * 4096);
    };
    auto wstore = [&]() {
        #pragma unroll
        for (int i = 0; i < 8; ++i) {
            int g = i * 4096 + t * 16;
            int row = g >> 9, slot = (g >> 4) & 31;
            *reinterpret_cast<short8*>(
                wchunk + row * 512 + ((slot ^ (row & 7)) * 16)) = wreg[i];
        }
    };

    wload(0);

    // stage X tile (fp32 -> bf16) into LDS
    #pragma unroll
    for (int i = 0; i < 16; ++i) {
        int idx = i * 256 + t;
        int row = idx >> 6;
        int c4 = (idx & 63) << 2;
        float4 v = *reinterpret_cast<const float4*>(x + (m0 + row) * CDIM + c4);
        ushort4 pk;
        pk.x = f2bf(v.x); pk.y = f2bf(v.y); pk.z = f2bf(v.z); pk.w = f2bf(v.w);
        *reinterpret_cast<ushort4*>(&xs[row * 256 + c4]) = pk;
    }
    __syncthreads();

    short8 a_frag[8];
    #pragma unroll
    for (int kk = 0; kk < 8; ++kk)
        a_frag[kk] = *reinterpret_cast<const short8*>(
            &xs[(wave * 16 + lr) * 256 + kk * 32 + lh * 8]);

    wstore();
    __syncthreads();
    wload(1);

    for (int j = 0; j < 12; ++j) {
        const int z = j >> 2, cc = j & 3;

        f32x4 acc[4];
        #pragma unroll
        for (int cb = 0; cb < 4; ++cb) acc[cb] = (f32x4)(0.0f);

        __builtin_amdgcn_s_setprio(1);
        #pragma unroll
        for (int kk = 0; kk < 8; ++kk) {
            #pragma unroll
            for (int cb = 0; cb < 4; ++cb) {
                short8 b_frag = *reinterpret_cast<const short8*>(
                    wchunk + (cb * 16 + lr) * 512 + (((kk * 4 + lh) ^ (lr & 7)) * 16));
                acc[cb] = mfma32(a_frag[kk], b_frag, acc[cb]);
            }
        }
        __builtin_amdgcn_s_setprio(0);

        if (z < 2) {
            const float* bias = (z == 0) ? bq : bk;
            const float bs = (z == 0) ? 0.0625f : 1.0f;
            #pragma unroll
            for (int cb = 0; cb < 4; ++cb) {
                int c = cc * 64 + cb * 16 + lr;
                float bb_ = bias[c] * bs;
                #pragma unroll
                for (int r = 0; r < 4; ++r)
                    xs[(wave * 16 + lh * 4 + r) * 256 + c] = f2bf(acc[cb][r] + bb_);
            }
        } else {
            char* xc = (char*)xs;
            #pragma unroll
            for (int cb = 0; cb < 4; ++cb) {
                int c = cc * 64 + cb * 16 + lr;
                float bb_ = bv[c];
                #pragma unroll
                for (int r = 0; r < 4; ++r) {
                    int n = wave * 16 + lh * 4 + r;
                    *reinterpret_cast<unsigned short*>(
                        xc + c * 128 + (((n >> 3) ^ (c & 7)) * 16) + (n & 7) * 2)
                        = f2bf(acc[cb][r] + bb_);
                }
            }
        }
        __syncthreads();

        if (cc == 3) {
            if (z == 0) {
                char* dst = (char*)q_ws + m0 * 512;
                const char* src = (const char*)xs;
                #pragma unroll
                for (int i = 0; i < 8; ++i) {
                    int g = i * 4096 + t * 16;
                    *reinterpret_cast<short8*>(dst + g) =
                        *reinterpret_cast<const short8*>(src + g);
                }
            } else if (z == 1) {
                char* dst = (char*)k_img + img_base;
                #pragma unroll
                for (int i = 0; i < 8; ++i) {
                    int g = i * 4096 + t * 16;
                    int row = g >> 9, sp = (g >> 4) & 31;
                    int s = sp ^ (row & 7);
                    *reinterpret_cast<short8*>(dst + g) =
                        *reinterpret_cast<const short8*>(&xs[row * 256 + s * 8]);
                }
            } else {
                char* dst = (char*)v_img + img_base;
                const char* src = (const char*)xs;
                #pragma unroll
                for (int i = 0; i < 8; ++i) {
                    int g = i * 4096 + t * 16;
                    *reinterpret_cast<short8*>(dst + g) =
                        *reinterpret_cast<const short8*>(src + g);
                }
            }
        }

        if (j < 11) wstore();
        if (j < 10) wload(j + 2);
        __syncthreads();
    }
}

// ---------- kernel 3: fused flash attention (32x32 MFMA) + projection + residual ----------
// 256 blocks, 8 waves x 32 q rows. Swapped QK^T via mfma_32x32x16 (lane owns one
// q column), in-register softmax (T12: cvt_pk + shfl_xor(32) P redistribution),
// full-rate 32x32 PV, global_load_lds double-buffered K/V staging.
__global__ __launch_bounds__(512, 2) void attn_kernel(
    const unsigned short* __restrict__ q_ws,
    const unsigned short* __restrict__ k_img,
    const unsigned short* __restrict__ v_img,
    const unsigned short* __restrict__ wpt,
    const float* __restrict__ bp,
    const float* __restrict__ x,
    float* __restrict__ out)
{
    extern __shared__ char smem[];
    char* ksb = smem;             // 2 x 32KB K tiles [64 k][512B], slot ^= row&7
    char* vsb = smem + 65536;     // 2 x 32KB V tiles [256 c][128B], slot ^= c&7
    const int t = threadIdx.x;
    const int wave = t >> 6, lane = t & 63;
    const int q32 = lane & 31;    // lane's q column (and K/V row index)
    const int u   = lane >> 5;
    const int lr = lane & 15, lh = lane >> 4;   // for 16x16 proj epilogue

    // XCD-aware mapping: batch b's 16 blocks all live on XCD b>>1
    const int bid = blockIdx.x;
    const int xcd = bid & 7, ii = bid >> 3;
    const int b = (xcd << 1) | (ii & 1);
    const int qc = ii >> 1;
    const long qbase = (long)b * NTOK + qc * 256 + wave * 32;

    const char* kg = (const char*)k_img + ((long)b * 64) * 32768;
    const char* vg = (const char*)v_img + ((long)b * 64) * 32768;

    // resident Q (B-operand): qf[kk] = Q[qbase+q32][kk*16 + u*8 .. +8], scale folded
    short8 qf[16];
    #pragma unroll
    for (int kk = 0; kk < 16; ++kk)
        qf[kk] = *reinterpret_cast<const short8*>(
            &q_ws[(qbase + q32) * 256 + kk * 16 + u * 8]);

    // acc[cb]: O^T[c = cb*32 + (r&3)+8*(r>>2)+4u][q32]
    f32x16 acc[8];
    #pragma unroll
    for (int cb = 0; cb < 8; ++cb) acc[cb] = (f32x16)(0.0f);
    float m_run = -INFINITY, l_run = 0.f;

    auto stage = [&](int nb, int tt) {
        const char* ks = kg + (long)tt * 32768 + wave * 4096 + lane * 16;
        char* kd = ksb + nb * 32768 + wave * 4096;
        #pragma unroll
        for (int i = 0; i < 4; ++i) ldsdma16(kd + i * 1024, ks + i * 1024);
        const char* vs = vg + (long)tt * 32768 + wave * 4096 + lane * 16;
        char* vd = vsb + nb * 32768 + wave * 4096;
        #pragma unroll
        for (int i = 0; i < 4; ++i) ldsdma16(vd + i * 1024, vs + i * 1024);
    };

    stage(0, 0);
    __syncthreads();

    for (int tt = 0; tt < 64; ++tt) {
        const int buf = tt & 1;
        if (tt < 63) stage(buf ^ 1, tt + 1);   // issue early; barrier drains it
        const char* kb = ksb + buf * 32768;
        const char* vb = vsb + buf * 32768;

        #pragma unroll
        for (int h = 0; h < 2; ++h) {
            // ---- QK^T: S^T[32 k][32 q] in one f32x16 ----
            f32x16 s = (f32x16)(0.0f);
            __builtin_amdgcn_s_setprio(1);
            #pragma unroll
            for (int kk = 0; kk < 16; ++kk) {
                short8 kf = *reinterpret_cast<const short8*>(
                    kb + (h * 32 + q32) * 512 + (((kk * 2 + u) ^ (q32 & 7)) * 16));
                s = mfma32x32(kf, qf[kk], s);
            }
            __builtin_amdgcn_s_setprio(0);

            // ---- in-register online softmax (lane owns q; 16 k vals + partner) ----
            float mt = fmaxf(fmaxf(fmaxf(s[0], s[1]), fmaxf(s[2], s[3])),
                             fmaxf(fmaxf(s[4], s[5]), fmaxf(s[6], s[7])));
            mt = fmaxf(mt, fmaxf(fmaxf(fmaxf(s[8], s[9]), fmaxf(s[10], s[11])),
                                 fmaxf(fmaxf(s[12], s[13]), fmaxf(s[14], s[15]))));
            mt = fmaxf(mt, __shfl_xor(mt, 32));
            if (!__all(mt <= m_run + 8.0f)) {     // defer-max (T13)
                float mn = fmaxf(m_run, mt);
                float a = __expf(m_run - mn);
                l_run *= a;
                #pragma unroll
                for (int cb = 0; cb < 8; ++cb)
                    #pragma unroll
                    for (int r = 0; r < 16; ++r) acc[cb][r] *= a;
                m_run = mn;
            }
            unsigned plo[4], phi[4];
            float rs = 0.f;
            #pragma unroll
            for (int m = 0; m < 4; ++m) {
                float e0 = __expf(s[4*m+0] - m_run);
                float e1 = __expf(s[4*m+1] - m_run);
                float e2 = __expf(s[4*m+2] - m_run);
                float e3 = __expf(s[4*m+3] - m_run);
                rs += (e0 + e1) + (e2 + e3);
                plo[m] = cvt_pk_bf16(e0, e1);   // k = 8m+4u+0,1
                phi[m] = cvt_pk_bf16(e2, e3);   // k = 8m+4u+2,3
            }
            rs += __shfl_xor(rs, 32);
            l_run += rs;

            // ---- PV: acc[c][q] += V^T[c][k16] @ P^T[k16][q], two K=16 steps ----
            #pragma unroll
            for (int tp = 0; tp < 2; ++tp) {
                // B-frag k = 16*tp + 8u + j. Lane (q,u) needs P_lo/P_hi[2tp+u]
                // from BOTH 32-lane halves (own + partner via shfl_xor 32).
                unsigned xl = plo[2*tp], yl = plo[2*tp+1];
                unsigned xh = phi[2*tp], yh = phi[2*tp+1];
                unsigned xls = __shfl_xor(xl, 32);
                unsigned yls = __shfl_xor(yl, 32);
                unsigned xhs = __shfl_xor(xh, 32);
                unsigned yhs = __shfl_xor(yh, 32);
                union { unsigned w[4]; short8 v; } pf;
                pf.w[0] = u ? yls : xl;    // k pair (16tp+8u+0,1)  from u_s=0
                pf.w[1] = u ? yhs : xh;    // k pair (+2,+3)        from u_s=0
                pf.w[2] = u ? yl  : xls;   // k pair (+4,+5)        from u_s=1
                pf.w[3] = u ? yh  : xhs;   // k pair (+6,+7)        from u_s=1
                __builtin_amdgcn_s_setprio(1);
                #pragma unroll
                for (int cb = 0; cb < 8; ++cb) {
                    int c = cb * 32 + q32;
                    short8 vf = *reinterpret_cast<const short8*>(
                        vb + c * 128 + (((h * 4 + 2 * tp + u) ^ (c & 7)) * 16));
                    acc[cb] = mfma32x32(vf, pf.v, acc[cb]);
                }
                __builtin_amdgcn_s_setprio(0);
            }
        }
        __syncthreads();   // drains DMA for tile tt+1; K/V readers done
    }

    // ---- epilogue: O^T -> per-wave LDS transpose (swizzled, paired b32 writes) ----
    __syncthreads();   // all waves done with ksb/vsb before overwriting with ot
    float inv = 1.0f / l_run;
    char* ot = smem + wave * 16384;   // [32 q][512B], slot ^= q&7
    #pragma unroll
    for (int cb = 0; cb < 8; ++cb) {
        #pragma unroll
        for (int i = 0; i < 8; ++i) {
            int c = cb * 32 + ((2 * i) & 3) + 8 * (i >> 1) + 4 * u;
            unsigned w = cvt_pk_bf16(acc[cb][2*i] * inv, acc[cb][2*i+1] * inv);
            *reinterpret_cast<unsigned*>(
                ot + q32 * 512 + (((c >> 3) ^ (q32 & 7)) * 16) + (c & 7) * 2) = w;
        }
    }

    // ---- fused projection: OUT = O @ Wp + bp + x (16x16x32, per-wave ot) ----
    f32x4 po[2][16];
    #pragma unroll
    for (int qb = 0; qb < 2; ++qb)
        #pragma unroll
        for (int cb = 0; cb < 16; ++cb) po[qb][cb] = (f32x4)(0.0f);

    for (int kk = 0; kk < 8; ++kk) {
        int slot = (kk * 4 + lh);
        short8 a0 = *reinterpret_cast<const short8*>(
            ot + (0 * 16 + lr) * 512 + ((slot ^ (lr & 7)) * 16));
        short8 a1 = *reinterpret_cast<const short8*>(
            ot + (1 * 16 + lr) * 512 + ((slot ^ (lr & 7)) * 16));
        #pragma unroll
        for (int cb = 0; cb < 16; ++cb) {
            short8 bf_ = *reinterpret_cast<const short8*>(
                &wpt[(cb * 16 + lr) * 256 + kk * 32 + lh * 8]);
            po[0][cb] = mfma32(a0, bf_, po[0][cb]);
            po[1][cb] = mfma32(a1, bf_, po[1][cb]);
        }
    }

    #pragma unroll
    for (int qb = 0; qb < 2; ++qb) {
        #pragma unroll
        for (int cb = 0; cb < 16; ++cb) {
            int c = cb * 16 + lr;
            float bias = bp[c];
            #pragma unroll
            for (int r = 0; r < 4; ++r) {
                long row = qbase + qb * 16 + lh * 4 + r;
                out[row * 256 + c] = po[qb][cb][r] + bias + x[row * 256 + c];
            }
        }
    }
}

extern "C" void kernel_launch(void* const* d_in, const int* in_sizes, int n_in,
                              void* d_out, int out_size, void* d_ws, size_t ws_size,
                              hipStream_t stream) {
    const float* x  = (const float*)d_in[0];
    const float* wq = (const float*)d_in[1];
    const float* bq = (const float*)d_in[2];
    const float* wk = (const float*)d_in[3];
    const float* bk = (const float*)d_in[4];
    const float* wv = (const float*)d_in[5];
    const float* bv = (const float*)d_in[6];
    const float* wp = (const float*)d_in[7];
    const float* bp = (const float*)d_in[8];
    float* out = (float*)d_out;

    char* ws = (char*)d_ws;
    unsigned short* wt_all = (unsigned short*)ws;               // 512 KiB
    unsigned short* q_ws   = (unsigned short*)(ws + 524288);    // 32 MiB
    unsigned short* k_img  = q_ws + (size_t)MROWS * CDIM;       // 32 MiB
    unsigned short* v_img  = k_img + (size_t)MROWS * CDIM;      // 32 MiB

    prep_w_kernel<<<dim3(256, 4), 256, 0, stream>>>(wq, wk, wv, wp, wt_all);
    qkv_kernel<<<dim3(MROWS / 64), 256, 0, stream>>>(x, wt_all, bq, bk, bv,
                                                     q_ws, k_img, v_img);
    hipFuncSetAttribute((const void*)attn_kernel,
                        hipFuncAttributeMaxDynamicSharedMemorySize, 131072);
    attn_kernel<<<dim3(256), 512, 131072, stream>>>(q_ws, k_img, v_img,
                                                    wt_all + 3 * 65536, bp, x, out);
}